// Round 4
// baseline (648.647 us; speedup 1.0000x reference)
//
#include <hip/hip_runtime.h>

// RNMF encoder, MI355X. Identities:
//   b_k = b_0 + H z_k  (ISTA scan telescopes) => z <- relu(b0 + H z - t), 16x
//   H z = [(1-0.1*eta) z_q - eta*D^T(u+z_m) ; (1-1.1*eta) z_m - eta*u], u = D z_q
// eta = 1/lambda_max(D^T D) via on-device power method on B = G^8/tr (17 iters,
// no per-iter normalization, final Rayleigh quotient; 1/8-root compresses error).
// R4 = R3 with device-legal powf (was host-only __exp2f/__log2f).

typedef __bf16 bf16x8 __attribute__((ext_vector_type(8)));
typedef __bf16 bf16x4 __attribute__((ext_vector_type(4)));
typedef float f32x4 __attribute__((ext_vector_type(4)));
typedef float f32x2 __attribute__((ext_vector_type(2)));

#define MFMA16(a, b, c) __builtin_amdgcn_mfma_f32_16x16x32_bf16((a), (b), (c), 0, 0, 0)

#define NTOT 65536
#define NCOL 32

__device__ __forceinline__ unsigned pk2(float a, float b) {
#if __has_builtin(__builtin_amdgcn_cvt_pk_bf16_f32)
  return __builtin_bit_cast(unsigned, __builtin_amdgcn_cvt_pk_bf16_f32(a, b));
#else
  unsigned short ua = __builtin_bit_cast(unsigned short, (__bf16)a);
  unsigned short ub = __builtin_bit_cast(unsigned short, (__bf16)b);
  return (unsigned)ua | ((unsigned)ub << 16);
#endif
}
__device__ __forceinline__ unsigned pk2v(f32x2 v) { return pk2(v[0], v[1]); }
__device__ __forceinline__ f32x2 f2(float s) { f32x2 v = {s, s}; return v; }
__device__ __forceinline__ f32x2 pfma(f32x2 a, f32x2 b, f32x2 c) {
  return __builtin_elementwise_fma(a, b, c);
}
__device__ __forceinline__ f32x2 pmax0(f32x2 a) {
  return __builtin_elementwise_max(a, f2(0.f));
}

// ---------------- Kernel 0: prep (1 block, 256 threads) ----------------
// ws: [0..255] header (wsf[0]=eta), +256: Dbf [256][64] bf16, +256+32768: DTbf [64][256] bf16.
__global__ void rnmf_prep(const float* __restrict__ D, void* __restrict__ ws) {
  float* wsf = (float*)ws;
  __bf16* Dbf = (__bf16*)((char*)ws + 256);
  __bf16* DTbf = (__bf16*)((char*)ws + 256 + 32768);

  __shared__ __bf16 DTl[64 * 264];   // D^T, [a][k] stride 264
  __shared__ __bf16 gA[64 * 72];
  __shared__ __bf16 gB[64 * 72];
  __shared__ float gf[64 * 68];      // G^8 fp32, stride 68 (272 B rows: conflict-free b128)
  __shared__ __align__(16) float xv[2][64];

  const int tid = threadIdx.x;
  const int w = tid >> 6, lane = tid & 63, c = lane & 15, q4 = lane >> 4;

  // load D (float4) once: export Dbf (coalesced) + scatter D^T into LDS
#pragma unroll
  for (int e = 0; e < 16; ++e) {
    int i4 = e * 256 + tid;                 // 4096 float4 = full D
    int row = i4 >> 4, col4 = (i4 & 15) * 4;
    float4 dv = *(const float4*)(D + i4 * 4);
    uint2 u; u.x = pk2(dv.x, dv.y); u.y = pk2(dv.z, dv.w);
    *(uint2*)(Dbf + i4 * 4) = u;
    DTl[(col4 + 0) * 264 + row] = (__bf16)dv.x;
    DTl[(col4 + 1) * 264 + row] = (__bf16)dv.y;
    DTl[(col4 + 2) * 264 + row] = (__bf16)dv.z;
    DTl[(col4 + 3) * 264 + row] = (__bf16)dv.w;
  }
  __syncthreads();
  // D^T bf16 out to ws (B-frag-friendly row-major [64][256])
#pragma unroll
  for (int e = 0; e < 8; ++e) {
    int fi = e * 256 + tid;
    int a = fi >> 5;
    int k = (fi * 8) & 255;
    *(bf16x8*)(DTbf + fi * 8) = *(const bf16x8*)&DTl[a * 264 + k];
  }
  // G = D^T D (symmetric; row-major buffer serves both A and B)
#pragma unroll
  for (int ct = 0; ct < 4; ++ct) {
    f32x4 acc = {0.f, 0.f, 0.f, 0.f};
#pragma unroll
    for (int kb = 0; kb < 8; ++kb) {
      bf16x8 a = *(const bf16x8*)&DTl[(16 * w + c) * 264 + 32 * kb + 8 * q4];
      bf16x8 b = *(const bf16x8*)&DTl[(16 * ct + c) * 264 + 32 * kb + 8 * q4];
      acc = MFMA16(a, b, acc);
    }
#pragma unroll
    for (int r = 0; r < 4; ++r)
      gA[(16 * w + 4 * q4 + r) * 72 + 16 * ct + c] = (__bf16)acc[r];
  }
  __syncthreads();
  // G2 (gA -> gB)
#pragma unroll
  for (int ct = 0; ct < 4; ++ct) {
    f32x4 acc = {0.f, 0.f, 0.f, 0.f};
#pragma unroll
    for (int kb = 0; kb < 2; ++kb) {
      bf16x8 a = *(const bf16x8*)&gA[(16 * w + c) * 72 + 32 * kb + 8 * q4];
      bf16x8 b = *(const bf16x8*)&gA[(16 * ct + c) * 72 + 32 * kb + 8 * q4];
      acc = MFMA16(a, b, acc);
    }
#pragma unroll
    for (int r = 0; r < 4; ++r)
      gB[(16 * w + 4 * q4 + r) * 72 + 16 * ct + c] = (__bf16)acc[r];
  }
  __syncthreads();
  // G4 (gB -> gA)
#pragma unroll
  for (int ct = 0; ct < 4; ++ct) {
    f32x4 acc = {0.f, 0.f, 0.f, 0.f};
#pragma unroll
    for (int kb = 0; kb < 2; ++kb) {
      bf16x8 a = *(const bf16x8*)&gB[(16 * w + c) * 72 + 32 * kb + 8 * q4];
      bf16x8 b = *(const bf16x8*)&gB[(16 * ct + c) * 72 + 32 * kb + 8 * q4];
      acc = MFMA16(a, b, acc);
    }
#pragma unroll
    for (int r = 0; r < 4; ++r)
      gA[(16 * w + 4 * q4 + r) * 72 + 16 * ct + c] = (__bf16)acc[r];
  }
  __syncthreads();
  // G8 (gA -> gf fp32)
#pragma unroll
  for (int ct = 0; ct < 4; ++ct) {
    f32x4 acc = {0.f, 0.f, 0.f, 0.f};
#pragma unroll
    for (int kb = 0; kb < 2; ++kb) {
      bf16x8 a = *(const bf16x8*)&gA[(16 * w + c) * 72 + 32 * kb + 8 * q4];
      bf16x8 b = *(const bf16x8*)&gA[(16 * ct + c) * 72 + 32 * kb + 8 * q4];
      acc = MFMA16(a, b, acc);
    }
#pragma unroll
    for (int r = 0; r < 4; ++r)
      gf[(16 * w + 4 * q4 + r) * 68 + 16 * ct + c] = acc[r];
  }
  __syncthreads();

  // Power method on B = G8/tr, all 4 waves redundantly (cheap barriers).
  // No per-iter normalization; Rayleigh quotient from last pair at the end.
  float td = gf[lane * 68 + lane];
#pragma unroll
  for (int off = 32; off; off >>= 1) td += __shfl_xor(td, off, 64);
  const float tr = td;
  const float itr = 1.f / tr;
  const int rowoff = lane * 68;
  float x = 1.f, xp = 1.f;
  for (int itp = 0; itp < 17; ++itp) {
    xv[itp & 1][lane] = x;
    __syncthreads();
    float a0 = 0.f, a1 = 0.f, a2 = 0.f, a3 = 0.f;
#pragma unroll
    for (int k = 0; k < 64; k += 16) {
      float4 g0 = *(const float4*)&gf[rowoff + k];
      float4 g1 = *(const float4*)&gf[rowoff + k + 4];
      float4 g2 = *(const float4*)&gf[rowoff + k + 8];
      float4 g3 = *(const float4*)&gf[rowoff + k + 12];
      float4 x0 = *(const float4*)&xv[itp & 1][k];
      float4 x1 = *(const float4*)&xv[itp & 1][k + 4];
      float4 x2 = *(const float4*)&xv[itp & 1][k + 8];
      float4 x3 = *(const float4*)&xv[itp & 1][k + 12];
      a0 = fmaf(g0.x, x0.x, a0); a0 = fmaf(g0.y, x0.y, a0);
      a0 = fmaf(g0.z, x0.z, a0); a0 = fmaf(g0.w, x0.w, a0);
      a1 = fmaf(g1.x, x1.x, a1); a1 = fmaf(g1.y, x1.y, a1);
      a1 = fmaf(g1.z, x1.z, a1); a1 = fmaf(g1.w, x1.w, a1);
      a2 = fmaf(g2.x, x2.x, a2); a2 = fmaf(g2.y, x2.y, a2);
      a2 = fmaf(g2.z, x2.z, a2); a2 = fmaf(g2.w, x2.w, a2);
      a3 = fmaf(g3.x, x3.x, a3); a3 = fmaf(g3.y, x3.y, a3);
      a3 = fmaf(g3.z, x3.z, a3); a3 = fmaf(g3.w, x3.w, a3);
    }
    xp = x;
    x = ((a0 + a1) + (a2 + a3)) * itr;     // x <- B xp
    if (itp == 8) x *= 1073741824.f;       // 2^30 range guard (pure scale)
  }
  float num = xp * x, den = xp * xp;       // mu = (xp.Bxp)/(xp.xp)
#pragma unroll
  for (int off = 32; off; off >>= 1) {
    num += __shfl_xor(num, off, 64);
    den += __shfl_xor(den, off, 64);
  }
  if (tid == 0)
    wsf[0] = powf((num / den) * tr, -0.125f);  // eta = (mu*tr)^(-1/8)
}

// ---------------- Kernel 1: main (2048 blocks x 256 thr, 32 cols/block) -----
// LDS arena (20480 B):
//   zqb: zq bf16 in B-frag order, 4096 B at +0
//   vb : 16384 B at +4096 — phase A: X tile bf16 in V(B-frag) layout;
//                           loop: V = u + z_m, same layout.
// B-frag addr of element (k,col): ct=col>>4, n=col&15:
//   4096 + ct*8192 + (k>>5)*1024 + (n + 16*((k>>3)&3))*16 + (k&7)*2
__global__ __launch_bounds__(256, 5) void rnmf_main(const float* __restrict__ X,
                                                    float* __restrict__ Z,
                                                    const void* __restrict__ ws) {
  const float* wsf = (const float*)ws;
  const __bf16* Dbf = (const __bf16*)((const char*)ws + 256);
  const __bf16* DTbf = (const __bf16*)((const char*)ws + 256 + 32768);

  __shared__ __align__(16) char arena[20480];
  char* smem = arena;

  const int tid = threadIdx.x;
  const int w = tid >> 6;
  const int lane = tid & 63;
  const int c = lane & 15;
  const int q4 = lane >> 4;
  const int q4h = q4 >> 1, q4l = q4 & 1;
  const int j0 = blockIdx.x * NCOL;

  // stage X tile straight into V-layout bf16 (coalesced float4 global reads)
#pragma unroll
  for (int e = 0; e < 8; ++e) {
    int idx = e * 256 + tid;                  // 2048 float4 = 256x32 tile
    int row = idx >> 3, c4 = (idx & 7) * 4;
    float4 g = *(const float4*)(X + row * NTOT + j0 + c4);
    int base = 4096 + (row >> 5) * 1024 + 256 * ((row >> 3) & 3) + (row & 7) * 2;
    float vals[4] = {g.x, g.y, g.z, g.w};
#pragma unroll
    for (int i = 0; i < 4; ++i) {
      int col = c4 + i;
      *(__bf16*)(smem + base + (col >> 4) * 8192 + (col & 15) * 16) = (__bf16)vals[i];
    }
  }

  const float eta = wsf[0];
  const f32x2 etav = f2(eta);
  const f32x2 metav = f2(-eta);
  const f32x2 cqv = f2(1.f - 0.1f * eta);
  const f32x2 cmv = f2(1.f - 1.1f * eta);
  const float tm = 0.1f * eta;

  // D fragments (iteration-invariant, VGPR-resident, from global/L2)
  bf16x8 d1[4][2];   // GEMM1 A: D rows [64w..64w+64), K=64
#pragma unroll
  for (int rt = 0; rt < 4; ++rt)
#pragma unroll
    for (int kb = 0; kb < 2; ++kb)
      d1[rt][kb] = *(const bf16x8*)(Dbf + (64 * w + 16 * rt + c) * 64 + 32 * kb + 8 * q4);
  bf16x8 d2[8];      // GEMM2 A: D^T rows [16w..16w+16), K=256
#pragma unroll
  for (int kb = 0; kb < 8; ++kb)
    d2[kb] = *(const bf16x8*)(DTbf + (16 * w + c) * 256 + 32 * kb + 8 * q4);

  __syncthreads();   // X staged

  const int rb = lane * 16;   // linear B-frag read base (conflict-free)

  // b0_q = eta * D^T x  (X already in B-frag layout)
  f32x2 bqt2[2][2];
#pragma unroll
  for (int ct = 0; ct < 2; ++ct) {
    f32x4 acc = {0.f, 0.f, 0.f, 0.f};
#pragma unroll
    for (int kb = 0; kb < 8; ++kb) {
      bf16x8 bx = *(const bf16x8*)(smem + rb + 4096 + ct * 8192 + kb * 1024);
      acc = MFMA16(d2[kb], bx, acc);
    }
    f32x2 a0 = {acc[0], acc[1]}, a1 = {acc[2], acc[3]};
    bqt2[ct][0] = etav * a0;   // t_q = 0
    bqt2[ct][1] = etav * a1;
  }

  // b0_m - t_m = eta*x - tm  (x from bf16 V-layout; 8B reads, 2-way max)
  f32x2 bmt2[4][2][2];
#pragma unroll
  for (int rt = 0; rt < 4; ++rt) {
    int r = 64 * w + 16 * rt + 4 * q4;
    int ao = 4096 + (r >> 5) * 1024 + (c + 16 * ((r >> 3) & 3)) * 16 + (r & 7) * 2;
#pragma unroll
    for (int ct = 0; ct < 2; ++ct) {
      bf16x4 xb = *(const bf16x4*)(smem + ao + ct * 8192);
      f32x2 x0 = {(float)xb[0], (float)xb[1]};
      f32x2 x1 = {(float)xb[2], (float)xb[3]};
      bmt2[rt][ct][0] = pfma(etav, x0, f2(-tm));
      bmt2[rt][ct][1] = pfma(etav, x1, f2(-tm));
    }
  }

  // z1 = relu(b0 - t)
  f32x2 zq2[2][2], zm2[4][2][2];
#pragma unroll
  for (int ct = 0; ct < 2; ++ct)
#pragma unroll
    for (int p = 0; p < 2; ++p) zq2[ct][p] = pmax0(bqt2[ct][p]);
#pragma unroll
  for (int rt = 0; rt < 4; ++rt)
#pragma unroll
    for (int ct = 0; ct < 2; ++ct)
#pragma unroll
      for (int p = 0; p < 2; ++p) zm2[rt][ct][p] = pmax0(bmt2[rt][ct][p]);

  // write offsets (C-layout -> B-frag layout), reads stay rb-linear
  const int wzq = (w >> 1) * 1024 + ((2 * w) & 3) * 256 + q4h * 256 + c * 16 + 8 * q4l;
  const int wvb = 4096 + 2 * w * 1024 + q4h * 256 + c * 16 + 8 * q4l;

  // publish z1_q (zqb region untouched by X staging)
#pragma unroll
  for (int ct = 0; ct < 2; ++ct) {
    uint2 u; u.x = pk2v(zq2[ct][0]); u.y = pk2v(zq2[ct][1]);
    *(uint2*)(smem + wzq + ct * 2048) = u;
  }

  for (int it = 0; it < 15; ++it) {
    __syncthreads();   // zqb ready; vb free (X reads / prior GEMM2 reads done)
    // GEMM1: U = D z_q ; z_m update ; publish V = u + z_m(old)
#pragma unroll
    for (int ct = 0; ct < 2; ++ct) {
      bf16x8 bz0 = *(const bf16x8*)(smem + rb + ct * 2048);
      bf16x8 bz1 = *(const bf16x8*)(smem + rb + ct * 2048 + 1024);
#pragma unroll
      for (int rt = 0; rt < 4; ++rt) {
        f32x4 acc = {0.f, 0.f, 0.f, 0.f};
        acc = MFMA16(d1[rt][0], bz0, acc);
        acc = MFMA16(d1[rt][1], bz1, acc);
        f32x2 u0 = {acc[0], acc[1]}, u1 = {acc[2], acc[3]};
        f32x2 z0 = zm2[rt][ct][0], z1 = zm2[rt][ct][1];
        f32x2 v0 = u0 + z0, v1 = u1 + z1;
        f32x2 t0 = pfma(cmv, z0, bmt2[rt][ct][0]);
        f32x2 t1 = pfma(cmv, z1, bmt2[rt][ct][1]);
        zm2[rt][ct][0] = pmax0(pfma(metav, u0, t0));
        zm2[rt][ct][1] = pmax0(pfma(metav, u1, t1));
        uint2 uu; uu.x = pk2v(v0); uu.y = pk2v(v1);
        *(uint2*)(smem + wvb + ct * 8192 + rt * 512) = uu;
      }
    }
    __syncthreads();   // vb ready; zqb free
    // GEMM2: w = D^T V ; z_q update ; publish
#pragma unroll
    for (int ct = 0; ct < 2; ++ct) {
      f32x4 acc = {0.f, 0.f, 0.f, 0.f};
#pragma unroll
      for (int kb = 0; kb < 8; ++kb) {
        bf16x8 bv = *(const bf16x8*)(smem + rb + 4096 + ct * 8192 + kb * 1024);
        acc = MFMA16(d2[kb], bv, acc);
      }
      f32x2 w0 = {acc[0], acc[1]}, w1 = {acc[2], acc[3]};
      f32x2 t0 = pfma(cqv, zq2[ct][0], bqt2[ct][0]);
      f32x2 t1 = pfma(cqv, zq2[ct][1], bqt2[ct][1]);
      zq2[ct][0] = pmax0(pfma(metav, w0, t0));
      zq2[ct][1] = pmax0(pfma(metav, w1, t1));
      uint2 u; u.x = pk2v(zq2[ct][0]); u.y = pk2v(zq2[ct][1]);
      *(uint2*)(smem + wzq + ct * 2048) = u;
    }
  }

  // store Z: rows 0..63 = q-part, rows 64..319 = m-part
#pragma unroll
  for (int ct = 0; ct < 2; ++ct)
#pragma unroll
    for (int p = 0; p < 2; ++p)
#pragma unroll
      for (int e = 0; e < 2; ++e)
        Z[(16 * w + 4 * q4 + 2 * p + e) * NTOT + j0 + 16 * ct + c] = zq2[ct][p][e];
#pragma unroll
  for (int rt = 0; rt < 4; ++rt)
#pragma unroll
    for (int ct = 0; ct < 2; ++ct)
#pragma unroll
      for (int p = 0; p < 2; ++p)
#pragma unroll
        for (int e = 0; e < 2; ++e)
          Z[(64 + 64 * w + 16 * rt + 4 * q4 + 2 * p + e) * NTOT + j0 + 16 * ct + c] = zm2[rt][ct][p][e];
}

extern "C" void kernel_launch(void* const* d_in, const int* in_sizes, int n_in,
                              void* d_out, int out_size, void* d_ws, size_t ws_size,
                              hipStream_t stream) {
  const float* X = (const float*)d_in[0];
  const float* D = (const float*)d_in[1];
  float* Z = (float*)d_out;
  rnmf_prep<<<dim3(1), dim3(256), 0, stream>>>(D, d_ws);
  rnmf_main<<<dim3(NTOT / NCOL), dim3(256), 0, stream>>>(X, Z, d_ws);
}

// Round 5
// 418.908 us; speedup vs baseline: 1.5484x; 1.5484x over previous
//
#include <hip/hip_runtime.h>

// RNMF encoder, MI355X. Identities:
//   b_k = b_0 + H z_k  (ISTA scan telescopes) => z <- relu(b0 + H z - t), 16x
//   H z = [(1-0.1*eta) z_q - eta*D^T(u+z_m) ; (1-1.1*eta) z_m - eta*u], u = D z_q
// eta = 1/lambda_max(D^T D) via on-device power method on B = G^8/tr.
// R5 = R4 with __launch_bounds__(256,4): the (256,5) bound capped the unified
// VGPR budget at ~102 and spilled D-fragments to scratch (FETCH 37MB->1.6GB,
// 527us). 128-VGPR budget removes the spill; LDS (20KB) still allows high occ.

typedef __bf16 bf16x8 __attribute__((ext_vector_type(8)));
typedef __bf16 bf16x4 __attribute__((ext_vector_type(4)));
typedef float f32x4 __attribute__((ext_vector_type(4)));
typedef float f32x2 __attribute__((ext_vector_type(2)));

#define MFMA16(a, b, c) __builtin_amdgcn_mfma_f32_16x16x32_bf16((a), (b), (c), 0, 0, 0)

#define NTOT 65536
#define NCOL 32

__device__ __forceinline__ unsigned pk2(float a, float b) {
#if __has_builtin(__builtin_amdgcn_cvt_pk_bf16_f32)
  return __builtin_bit_cast(unsigned, __builtin_amdgcn_cvt_pk_bf16_f32(a, b));
#else
  unsigned short ua = __builtin_bit_cast(unsigned short, (__bf16)a);
  unsigned short ub = __builtin_bit_cast(unsigned short, (__bf16)b);
  return (unsigned)ua | ((unsigned)ub << 16);
#endif
}
__device__ __forceinline__ unsigned pk2v(f32x2 v) { return pk2(v[0], v[1]); }
__device__ __forceinline__ f32x2 f2(float s) { f32x2 v = {s, s}; return v; }
__device__ __forceinline__ f32x2 pfma(f32x2 a, f32x2 b, f32x2 c) {
  return __builtin_elementwise_fma(a, b, c);
}
__device__ __forceinline__ f32x2 pmax0(f32x2 a) {
  return __builtin_elementwise_max(a, f2(0.f));
}

// ---------------- Kernel 0: prep (1 block, 256 threads) ----------------
// ws: [0..255] header (wsf[0]=eta), +256: Dbf [256][64] bf16, +256+32768: DTbf [64][256] bf16.
__global__ void rnmf_prep(const float* __restrict__ D, void* __restrict__ ws) {
  float* wsf = (float*)ws;
  __bf16* Dbf = (__bf16*)((char*)ws + 256);
  __bf16* DTbf = (__bf16*)((char*)ws + 256 + 32768);

  __shared__ __bf16 DTl[64 * 264];   // D^T, [a][k] stride 264
  __shared__ __bf16 gA[64 * 72];
  __shared__ __bf16 gB[64 * 72];
  __shared__ float gf[64 * 68];      // G^8 fp32, stride 68 (272 B rows: conflict-free b128)
  __shared__ __align__(16) float xv[2][64];

  const int tid = threadIdx.x;
  const int w = tid >> 6, lane = tid & 63, c = lane & 15, q4 = lane >> 4;

  // load D (float4) once: export Dbf (coalesced) + scatter D^T into LDS
#pragma unroll
  for (int e = 0; e < 16; ++e) {
    int i4 = e * 256 + tid;                 // 4096 float4 = full D
    int row = i4 >> 4, col4 = (i4 & 15) * 4;
    float4 dv = *(const float4*)(D + i4 * 4);
    uint2 u; u.x = pk2(dv.x, dv.y); u.y = pk2(dv.z, dv.w);
    *(uint2*)(Dbf + i4 * 4) = u;
    DTl[(col4 + 0) * 264 + row] = (__bf16)dv.x;
    DTl[(col4 + 1) * 264 + row] = (__bf16)dv.y;
    DTl[(col4 + 2) * 264 + row] = (__bf16)dv.z;
    DTl[(col4 + 3) * 264 + row] = (__bf16)dv.w;
  }
  __syncthreads();
  // D^T bf16 out to ws (B-frag-friendly row-major [64][256])
#pragma unroll
  for (int e = 0; e < 8; ++e) {
    int fi = e * 256 + tid;
    int a = fi >> 5;
    int k = (fi * 8) & 255;
    *(bf16x8*)(DTbf + fi * 8) = *(const bf16x8*)&DTl[a * 264 + k];
  }
  // G = D^T D (symmetric; row-major buffer serves both A and B)
#pragma unroll
  for (int ct = 0; ct < 4; ++ct) {
    f32x4 acc = {0.f, 0.f, 0.f, 0.f};
#pragma unroll
    for (int kb = 0; kb < 8; ++kb) {
      bf16x8 a = *(const bf16x8*)&DTl[(16 * w + c) * 264 + 32 * kb + 8 * q4];
      bf16x8 b = *(const bf16x8*)&DTl[(16 * ct + c) * 264 + 32 * kb + 8 * q4];
      acc = MFMA16(a, b, acc);
    }
#pragma unroll
    for (int r = 0; r < 4; ++r)
      gA[(16 * w + 4 * q4 + r) * 72 + 16 * ct + c] = (__bf16)acc[r];
  }
  __syncthreads();
  // G2 (gA -> gB)
#pragma unroll
  for (int ct = 0; ct < 4; ++ct) {
    f32x4 acc = {0.f, 0.f, 0.f, 0.f};
#pragma unroll
    for (int kb = 0; kb < 2; ++kb) {
      bf16x8 a = *(const bf16x8*)&gA[(16 * w + c) * 72 + 32 * kb + 8 * q4];
      bf16x8 b = *(const bf16x8*)&gA[(16 * ct + c) * 72 + 32 * kb + 8 * q4];
      acc = MFMA16(a, b, acc);
    }
#pragma unroll
    for (int r = 0; r < 4; ++r)
      gB[(16 * w + 4 * q4 + r) * 72 + 16 * ct + c] = (__bf16)acc[r];
  }
  __syncthreads();
  // G4 (gB -> gA)
#pragma unroll
  for (int ct = 0; ct < 4; ++ct) {
    f32x4 acc = {0.f, 0.f, 0.f, 0.f};
#pragma unroll
    for (int kb = 0; kb < 2; ++kb) {
      bf16x8 a = *(const bf16x8*)&gB[(16 * w + c) * 72 + 32 * kb + 8 * q4];
      bf16x8 b = *(const bf16x8*)&gB[(16 * ct + c) * 72 + 32 * kb + 8 * q4];
      acc = MFMA16(a, b, acc);
    }
#pragma unroll
    for (int r = 0; r < 4; ++r)
      gA[(16 * w + 4 * q4 + r) * 72 + 16 * ct + c] = (__bf16)acc[r];
  }
  __syncthreads();
  // G8 (gA -> gf fp32)
#pragma unroll
  for (int ct = 0; ct < 4; ++ct) {
    f32x4 acc = {0.f, 0.f, 0.f, 0.f};
#pragma unroll
    for (int kb = 0; kb < 2; ++kb) {
      bf16x8 a = *(const bf16x8*)&gA[(16 * w + c) * 72 + 32 * kb + 8 * q4];
      bf16x8 b = *(const bf16x8*)&gA[(16 * ct + c) * 72 + 32 * kb + 8 * q4];
      acc = MFMA16(a, b, acc);
    }
#pragma unroll
    for (int r = 0; r < 4; ++r)
      gf[(16 * w + 4 * q4 + r) * 68 + 16 * ct + c] = acc[r];
  }
  __syncthreads();

  // Power method on B = G8/tr, all 4 waves redundantly (cheap barriers).
  // No per-iter normalization; Rayleigh quotient from last pair at the end.
  float td = gf[lane * 68 + lane];
#pragma unroll
  for (int off = 32; off; off >>= 1) td += __shfl_xor(td, off, 64);
  const float tr = td;
  const float itr = 1.f / tr;
  const int rowoff = lane * 68;
  float x = 1.f, xp = 1.f;
  for (int itp = 0; itp < 17; ++itp) {
    xv[itp & 1][lane] = x;
    __syncthreads();
    float a0 = 0.f, a1 = 0.f, a2 = 0.f, a3 = 0.f;
#pragma unroll
    for (int k = 0; k < 64; k += 16) {
      float4 g0 = *(const float4*)&gf[rowoff + k];
      float4 g1 = *(const float4*)&gf[rowoff + k + 4];
      float4 g2 = *(const float4*)&gf[rowoff + k + 8];
      float4 g3 = *(const float4*)&gf[rowoff + k + 12];
      float4 x0 = *(const float4*)&xv[itp & 1][k];
      float4 x1 = *(const float4*)&xv[itp & 1][k + 4];
      float4 x2 = *(const float4*)&xv[itp & 1][k + 8];
      float4 x3 = *(const float4*)&xv[itp & 1][k + 12];
      a0 = fmaf(g0.x, x0.x, a0); a0 = fmaf(g0.y, x0.y, a0);
      a0 = fmaf(g0.z, x0.z, a0); a0 = fmaf(g0.w, x0.w, a0);
      a1 = fmaf(g1.x, x1.x, a1); a1 = fmaf(g1.y, x1.y, a1);
      a1 = fmaf(g1.z, x1.z, a1); a1 = fmaf(g1.w, x1.w, a1);
      a2 = fmaf(g2.x, x2.x, a2); a2 = fmaf(g2.y, x2.y, a2);
      a2 = fmaf(g2.z, x2.z, a2); a2 = fmaf(g2.w, x2.w, a2);
      a3 = fmaf(g3.x, x3.x, a3); a3 = fmaf(g3.y, x3.y, a3);
      a3 = fmaf(g3.z, x3.z, a3); a3 = fmaf(g3.w, x3.w, a3);
    }
    xp = x;
    x = ((a0 + a1) + (a2 + a3)) * itr;     // x <- B xp
    if (itp == 8) x *= 1073741824.f;       // 2^30 range guard (pure scale)
  }
  float num = xp * x, den = xp * xp;       // mu = (xp.Bxp)/(xp.xp)
#pragma unroll
  for (int off = 32; off; off >>= 1) {
    num += __shfl_xor(num, off, 64);
    den += __shfl_xor(den, off, 64);
  }
  if (tid == 0)
    wsf[0] = powf((num / den) * tr, -0.125f);  // eta = (mu*tr)^(-1/8)
}

// ---------------- Kernel 1: main (2048 blocks x 256 thr, 32 cols/block) -----
// LDS arena (20480 B):
//   zqb: zq bf16 in B-frag order, 4096 B at +0
//   vb : 16384 B at +4096 — phase A: X tile bf16 in V(B-frag) layout;
//                           loop: V = u + z_m, same layout.
// B-frag addr of element (k,col): ct=col>>4, n=col&15:
//   4096 + ct*8192 + (k>>5)*1024 + (n + 16*((k>>3)&3))*16 + (k&7)*2
__global__ __launch_bounds__(256, 4) void rnmf_main(const float* __restrict__ X,
                                                    float* __restrict__ Z,
                                                    const void* __restrict__ ws) {
  const float* wsf = (const float*)ws;
  const __bf16* Dbf = (const __bf16*)((const char*)ws + 256);
  const __bf16* DTbf = (const __bf16*)((const char*)ws + 256 + 32768);

  __shared__ __align__(16) char arena[20480];
  char* smem = arena;

  const int tid = threadIdx.x;
  const int w = tid >> 6;
  const int lane = tid & 63;
  const int c = lane & 15;
  const int q4 = lane >> 4;
  const int q4h = q4 >> 1, q4l = q4 & 1;
  const int j0 = blockIdx.x * NCOL;

  // stage X tile straight into V-layout bf16 (coalesced float4 global reads)
#pragma unroll
  for (int e = 0; e < 8; ++e) {
    int idx = e * 256 + tid;                  // 2048 float4 = 256x32 tile
    int row = idx >> 3, c4 = (idx & 7) * 4;
    float4 g = *(const float4*)(X + row * NTOT + j0 + c4);
    int base = 4096 + (row >> 5) * 1024 + 256 * ((row >> 3) & 3) + (row & 7) * 2;
    float vals[4] = {g.x, g.y, g.z, g.w};
#pragma unroll
    for (int i = 0; i < 4; ++i) {
      int col = c4 + i;
      *(__bf16*)(smem + base + (col >> 4) * 8192 + (col & 15) * 16) = (__bf16)vals[i];
    }
  }

  const float eta = wsf[0];
  const f32x2 etav = f2(eta);
  const f32x2 metav = f2(-eta);
  const f32x2 cqv = f2(1.f - 0.1f * eta);
  const f32x2 cmv = f2(1.f - 1.1f * eta);
  const float tm = 0.1f * eta;

  // D fragments (iteration-invariant, VGPR-resident, from global/L2)
  bf16x8 d1[4][2];   // GEMM1 A: D rows [64w..64w+64), K=64
#pragma unroll
  for (int rt = 0; rt < 4; ++rt)
#pragma unroll
    for (int kb = 0; kb < 2; ++kb)
      d1[rt][kb] = *(const bf16x8*)(Dbf + (64 * w + 16 * rt + c) * 64 + 32 * kb + 8 * q4);
  bf16x8 d2[8];      // GEMM2 A: D^T rows [16w..16w+16), K=256
#pragma unroll
  for (int kb = 0; kb < 8; ++kb)
    d2[kb] = *(const bf16x8*)(DTbf + (16 * w + c) * 256 + 32 * kb + 8 * q4);

  __syncthreads();   // X staged

  const int rb = lane * 16;   // linear B-frag read base (conflict-free)

  // b0_q = eta * D^T x  (X already in B-frag layout)
  f32x2 bqt2[2][2];
#pragma unroll
  for (int ct = 0; ct < 2; ++ct) {
    f32x4 acc = {0.f, 0.f, 0.f, 0.f};
#pragma unroll
    for (int kb = 0; kb < 8; ++kb) {
      bf16x8 bx = *(const bf16x8*)(smem + rb + 4096 + ct * 8192 + kb * 1024);
      acc = MFMA16(d2[kb], bx, acc);
    }
    f32x2 a0 = {acc[0], acc[1]}, a1 = {acc[2], acc[3]};
    bqt2[ct][0] = etav * a0;   // t_q = 0
    bqt2[ct][1] = etav * a1;
  }

  // b0_m - t_m = eta*x - tm  (x from bf16 V-layout; 8B reads, 2-way max)
  f32x2 bmt2[4][2][2];
#pragma unroll
  for (int rt = 0; rt < 4; ++rt) {
    int r = 64 * w + 16 * rt + 4 * q4;
    int ao = 4096 + (r >> 5) * 1024 + (c + 16 * ((r >> 3) & 3)) * 16 + (r & 7) * 2;
#pragma unroll
    for (int ct = 0; ct < 2; ++ct) {
      bf16x4 xb = *(const bf16x4*)(smem + ao + ct * 8192);
      f32x2 x0 = {(float)xb[0], (float)xb[1]};
      f32x2 x1 = {(float)xb[2], (float)xb[3]};
      bmt2[rt][ct][0] = pfma(etav, x0, f2(-tm));
      bmt2[rt][ct][1] = pfma(etav, x1, f2(-tm));
    }
  }

  // z1 = relu(b0 - t)
  f32x2 zq2[2][2], zm2[4][2][2];
#pragma unroll
  for (int ct = 0; ct < 2; ++ct)
#pragma unroll
    for (int p = 0; p < 2; ++p) zq2[ct][p] = pmax0(bqt2[ct][p]);
#pragma unroll
  for (int rt = 0; rt < 4; ++rt)
#pragma unroll
    for (int ct = 0; ct < 2; ++ct)
#pragma unroll
      for (int p = 0; p < 2; ++p) zm2[rt][ct][p] = pmax0(bmt2[rt][ct][p]);

  // write offsets (C-layout -> B-frag layout), reads stay rb-linear
  const int wzq = (w >> 1) * 1024 + ((2 * w) & 3) * 256 + q4h * 256 + c * 16 + 8 * q4l;
  const int wvb = 4096 + 2 * w * 1024 + q4h * 256 + c * 16 + 8 * q4l;

  // publish z1_q (zqb region untouched by X staging)
#pragma unroll
  for (int ct = 0; ct < 2; ++ct) {
    uint2 u; u.x = pk2v(zq2[ct][0]); u.y = pk2v(zq2[ct][1]);
    *(uint2*)(smem + wzq + ct * 2048) = u;
  }

  for (int it = 0; it < 15; ++it) {
    __syncthreads();   // zqb ready; vb free (X reads / prior GEMM2 reads done)
    // GEMM1: U = D z_q ; z_m update ; publish V = u + z_m(old)
#pragma unroll
    for (int ct = 0; ct < 2; ++ct) {
      bf16x8 bz0 = *(const bf16x8*)(smem + rb + ct * 2048);
      bf16x8 bz1 = *(const bf16x8*)(smem + rb + ct * 2048 + 1024);
#pragma unroll
      for (int rt = 0; rt < 4; ++rt) {
        f32x4 acc = {0.f, 0.f, 0.f, 0.f};
        acc = MFMA16(d1[rt][0], bz0, acc);
        acc = MFMA16(d1[rt][1], bz1, acc);
        f32x2 u0 = {acc[0], acc[1]}, u1 = {acc[2], acc[3]};
        f32x2 z0 = zm2[rt][ct][0], z1 = zm2[rt][ct][1];
        f32x2 v0 = u0 + z0, v1 = u1 + z1;
        f32x2 t0 = pfma(cmv, z0, bmt2[rt][ct][0]);
        f32x2 t1 = pfma(cmv, z1, bmt2[rt][ct][1]);
        zm2[rt][ct][0] = pmax0(pfma(metav, u0, t0));
        zm2[rt][ct][1] = pmax0(pfma(metav, u1, t1));
        uint2 uu; uu.x = pk2v(v0); uu.y = pk2v(v1);
        *(uint2*)(smem + wvb + ct * 8192 + rt * 512) = uu;
      }
    }
    __syncthreads();   // vb ready; zqb free
    // GEMM2: w = D^T V ; z_q update ; publish
#pragma unroll
    for (int ct = 0; ct < 2; ++ct) {
      f32x4 acc = {0.f, 0.f, 0.f, 0.f};
#pragma unroll
      for (int kb = 0; kb < 8; ++kb) {
        bf16x8 bv = *(const bf16x8*)(smem + rb + 4096 + ct * 8192 + kb * 1024);
        acc = MFMA16(d2[kb], bv, acc);
      }
      f32x2 w0 = {acc[0], acc[1]}, w1 = {acc[2], acc[3]};
      f32x2 t0 = pfma(cqv, zq2[ct][0], bqt2[ct][0]);
      f32x2 t1 = pfma(cqv, zq2[ct][1], bqt2[ct][1]);
      zq2[ct][0] = pmax0(pfma(metav, w0, t0));
      zq2[ct][1] = pmax0(pfma(metav, w1, t1));
      uint2 u; u.x = pk2v(zq2[ct][0]); u.y = pk2v(zq2[ct][1]);
      *(uint2*)(smem + wzq + ct * 2048) = u;
    }
  }

  // store Z: rows 0..63 = q-part, rows 64..319 = m-part
#pragma unroll
  for (int ct = 0; ct < 2; ++ct)
#pragma unroll
    for (int p = 0; p < 2; ++p)
#pragma unroll
      for (int e = 0; e < 2; ++e)
        Z[(16 * w + 4 * q4 + 2 * p + e) * NTOT + j0 + 16 * ct + c] = zq2[ct][p][e];
#pragma unroll
  for (int rt = 0; rt < 4; ++rt)
#pragma unroll
    for (int ct = 0; ct < 2; ++ct)
#pragma unroll
      for (int p = 0; p < 2; ++p)
#pragma unroll
        for (int e = 0; e < 2; ++e)
          Z[(64 + 64 * w + 16 * rt + 4 * q4 + 2 * p + e) * NTOT + j0 + 16 * ct + c] = zm2[rt][ct][p][e];
}

extern "C" void kernel_launch(void* const* d_in, const int* in_sizes, int n_in,
                              void* d_out, int out_size, void* d_ws, size_t ws_size,
                              hipStream_t stream) {
  const float* X = (const float*)d_in[0];
  const float* D = (const float*)d_in[1];
  float* Z = (float*)d_out;
  rnmf_prep<<<dim3(1), dim3(256), 0, stream>>>(D, d_ws);
  rnmf_main<<<dim3(NTOT / NCOL), dim3(256), 0, stream>>>(X, Z, d_ws);
}

// Round 6
// 231.373 us; speedup vs baseline: 2.8035x; 1.8105x over previous
//
#include <hip/hip_runtime.h>

// RNMF encoder, MI355X. Identities:
//   b_k = b_0 + H z_k  (ISTA scan telescopes) => z <- relu(b0 + H z - t), 16x
//   H z = [(1-0.1*eta) z_q - eta*D^T(u+z_m) ; (1-1.1*eta) z_m - eta*u], u = D z_q
// eta = 1/lambda_max(D^T D) via on-device power method on B = G^8/tr.
// R6 = R5 with __launch_bounds__(256,3): (256,4) still spilled (VGPR capped at
// 64, FETCH 740MB of scratch). (256,3) is R2's proven spill-free point (VGPR 84,
// FETCH 37MB); this kernel has LESS register pressure than R2, same LDS 20KB.

typedef __bf16 bf16x8 __attribute__((ext_vector_type(8)));
typedef __bf16 bf16x4 __attribute__((ext_vector_type(4)));
typedef float f32x4 __attribute__((ext_vector_type(4)));
typedef float f32x2 __attribute__((ext_vector_type(2)));

#define MFMA16(a, b, c) __builtin_amdgcn_mfma_f32_16x16x32_bf16((a), (b), (c), 0, 0, 0)

#define NTOT 65536
#define NCOL 32

__device__ __forceinline__ unsigned pk2(float a, float b) {
#if __has_builtin(__builtin_amdgcn_cvt_pk_bf16_f32)
  return __builtin_bit_cast(unsigned, __builtin_amdgcn_cvt_pk_bf16_f32(a, b));
#else
  unsigned short ua = __builtin_bit_cast(unsigned short, (__bf16)a);
  unsigned short ub = __builtin_bit_cast(unsigned short, (__bf16)b);
  return (unsigned)ua | ((unsigned)ub << 16);
#endif
}
__device__ __forceinline__ unsigned pk2v(f32x2 v) { return pk2(v[0], v[1]); }
__device__ __forceinline__ f32x2 f2(float s) { f32x2 v = {s, s}; return v; }
__device__ __forceinline__ f32x2 pfma(f32x2 a, f32x2 b, f32x2 c) {
  return __builtin_elementwise_fma(a, b, c);
}
__device__ __forceinline__ f32x2 pmax0(f32x2 a) {
  return __builtin_elementwise_max(a, f2(0.f));
}

// ---------------- Kernel 0: prep (1 block, 256 threads) ----------------
// ws: [0..255] header (wsf[0]=eta), +256: Dbf [256][64] bf16, +256+32768: DTbf [64][256] bf16.
__global__ void rnmf_prep(const float* __restrict__ D, void* __restrict__ ws) {
  float* wsf = (float*)ws;
  __bf16* Dbf = (__bf16*)((char*)ws + 256);
  __bf16* DTbf = (__bf16*)((char*)ws + 256 + 32768);

  __shared__ __bf16 DTl[64 * 264];   // D^T, [a][k] stride 264
  __shared__ __bf16 gA[64 * 72];
  __shared__ __bf16 gB[64 * 72];
  __shared__ float gf[64 * 68];      // G^8 fp32, stride 68 (272 B rows: conflict-free b128)
  __shared__ __align__(16) float xv[2][64];

  const int tid = threadIdx.x;
  const int w = tid >> 6, lane = tid & 63, c = lane & 15, q4 = lane >> 4;

  // load D (float4) once: export Dbf (coalesced) + scatter D^T into LDS
#pragma unroll
  for (int e = 0; e < 16; ++e) {
    int i4 = e * 256 + tid;                 // 4096 float4 = full D
    int row = i4 >> 4, col4 = (i4 & 15) * 4;
    float4 dv = *(const float4*)(D + i4 * 4);
    uint2 u; u.x = pk2(dv.x, dv.y); u.y = pk2(dv.z, dv.w);
    *(uint2*)(Dbf + i4 * 4) = u;
    DTl[(col4 + 0) * 264 + row] = (__bf16)dv.x;
    DTl[(col4 + 1) * 264 + row] = (__bf16)dv.y;
    DTl[(col4 + 2) * 264 + row] = (__bf16)dv.z;
    DTl[(col4 + 3) * 264 + row] = (__bf16)dv.w;
  }
  __syncthreads();
  // D^T bf16 out to ws (B-frag-friendly row-major [64][256])
#pragma unroll
  for (int e = 0; e < 8; ++e) {
    int fi = e * 256 + tid;
    int a = fi >> 5;
    int k = (fi * 8) & 255;
    *(bf16x8*)(DTbf + fi * 8) = *(const bf16x8*)&DTl[a * 264 + k];
  }
  // G = D^T D (symmetric; row-major buffer serves both A and B)
#pragma unroll
  for (int ct = 0; ct < 4; ++ct) {
    f32x4 acc = {0.f, 0.f, 0.f, 0.f};
#pragma unroll
    for (int kb = 0; kb < 8; ++kb) {
      bf16x8 a = *(const bf16x8*)&DTl[(16 * w + c) * 264 + 32 * kb + 8 * q4];
      bf16x8 b = *(const bf16x8*)&DTl[(16 * ct + c) * 264 + 32 * kb + 8 * q4];
      acc = MFMA16(a, b, acc);
    }
#pragma unroll
    for (int r = 0; r < 4; ++r)
      gA[(16 * w + 4 * q4 + r) * 72 + 16 * ct + c] = (__bf16)acc[r];
  }
  __syncthreads();
  // G2 (gA -> gB)
#pragma unroll
  for (int ct = 0; ct < 4; ++ct) {
    f32x4 acc = {0.f, 0.f, 0.f, 0.f};
#pragma unroll
    for (int kb = 0; kb < 2; ++kb) {
      bf16x8 a = *(const bf16x8*)&gA[(16 * w + c) * 72 + 32 * kb + 8 * q4];
      bf16x8 b = *(const bf16x8*)&gA[(16 * ct + c) * 72 + 32 * kb + 8 * q4];
      acc = MFMA16(a, b, acc);
    }
#pragma unroll
    for (int r = 0; r < 4; ++r)
      gB[(16 * w + 4 * q4 + r) * 72 + 16 * ct + c] = (__bf16)acc[r];
  }
  __syncthreads();
  // G4 (gB -> gA)
#pragma unroll
  for (int ct = 0; ct < 4; ++ct) {
    f32x4 acc = {0.f, 0.f, 0.f, 0.f};
#pragma unroll
    for (int kb = 0; kb < 2; ++kb) {
      bf16x8 a = *(const bf16x8*)&gB[(16 * w + c) * 72 + 32 * kb + 8 * q4];
      bf16x8 b = *(const bf16x8*)&gB[(16 * ct + c) * 72 + 32 * kb + 8 * q4];
      acc = MFMA16(a, b, acc);
    }
#pragma unroll
    for (int r = 0; r < 4; ++r)
      gA[(16 * w + 4 * q4 + r) * 72 + 16 * ct + c] = (__bf16)acc[r];
  }
  __syncthreads();
  // G8 (gA -> gf fp32)
#pragma unroll
  for (int ct = 0; ct < 4; ++ct) {
    f32x4 acc = {0.f, 0.f, 0.f, 0.f};
#pragma unroll
    for (int kb = 0; kb < 2; ++kb) {
      bf16x8 a = *(const bf16x8*)&gA[(16 * w + c) * 72 + 32 * kb + 8 * q4];
      bf16x8 b = *(const bf16x8*)&gA[(16 * ct + c) * 72 + 32 * kb + 8 * q4];
      acc = MFMA16(a, b, acc);
    }
#pragma unroll
    for (int r = 0; r < 4; ++r)
      gf[(16 * w + 4 * q4 + r) * 68 + 16 * ct + c] = acc[r];
  }
  __syncthreads();

  // Power method on B = G8/tr, all 4 waves redundantly (cheap barriers).
  // No per-iter normalization; Rayleigh quotient from last pair at the end.
  float td = gf[lane * 68 + lane];
#pragma unroll
  for (int off = 32; off; off >>= 1) td += __shfl_xor(td, off, 64);
  const float tr = td;
  const float itr = 1.f / tr;
  const int rowoff = lane * 68;
  float x = 1.f, xp = 1.f;
  for (int itp = 0; itp < 17; ++itp) {
    xv[itp & 1][lane] = x;
    __syncthreads();
    float a0 = 0.f, a1 = 0.f, a2 = 0.f, a3 = 0.f;
#pragma unroll
    for (int k = 0; k < 64; k += 16) {
      float4 g0 = *(const float4*)&gf[rowoff + k];
      float4 g1 = *(const float4*)&gf[rowoff + k + 4];
      float4 g2 = *(const float4*)&gf[rowoff + k + 8];
      float4 g3 = *(const float4*)&gf[rowoff + k + 12];
      float4 x0 = *(const float4*)&xv[itp & 1][k];
      float4 x1 = *(const float4*)&xv[itp & 1][k + 4];
      float4 x2 = *(const float4*)&xv[itp & 1][k + 8];
      float4 x3 = *(const float4*)&xv[itp & 1][k + 12];
      a0 = fmaf(g0.x, x0.x, a0); a0 = fmaf(g0.y, x0.y, a0);
      a0 = fmaf(g0.z, x0.z, a0); a0 = fmaf(g0.w, x0.w, a0);
      a1 = fmaf(g1.x, x1.x, a1); a1 = fmaf(g1.y, x1.y, a1);
      a1 = fmaf(g1.z, x1.z, a1); a1 = fmaf(g1.w, x1.w, a1);
      a2 = fmaf(g2.x, x2.x, a2); a2 = fmaf(g2.y, x2.y, a2);
      a2 = fmaf(g2.z, x2.z, a2); a2 = fmaf(g2.w, x2.w, a2);
      a3 = fmaf(g3.x, x3.x, a3); a3 = fmaf(g3.y, x3.y, a3);
      a3 = fmaf(g3.z, x3.z, a3); a3 = fmaf(g3.w, x3.w, a3);
    }
    xp = x;
    x = ((a0 + a1) + (a2 + a3)) * itr;     // x <- B xp
    if (itp == 8) x *= 1073741824.f;       // 2^30 range guard (pure scale)
  }
  float num = xp * x, den = xp * xp;       // mu = (xp.Bxp)/(xp.xp)
#pragma unroll
  for (int off = 32; off; off >>= 1) {
    num += __shfl_xor(num, off, 64);
    den += __shfl_xor(den, off, 64);
  }
  if (tid == 0)
    wsf[0] = powf((num / den) * tr, -0.125f);  // eta = (mu*tr)^(-1/8)
}

// ---------------- Kernel 1: main (2048 blocks x 256 thr, 32 cols/block) -----
// LDS arena (20480 B):
//   zqb: zq bf16 in B-frag order, 4096 B at +0
//   vb : 16384 B at +4096 — phase A: X tile bf16 in V(B-frag) layout;
//                           loop: V = u + z_m, same layout.
// B-frag addr of element (k,col): ct=col>>4, n=col&15:
//   4096 + ct*8192 + (k>>5)*1024 + (n + 16*((k>>3)&3))*16 + (k&7)*2
__global__ __launch_bounds__(256, 3) void rnmf_main(const float* __restrict__ X,
                                                    float* __restrict__ Z,
                                                    const void* __restrict__ ws) {
  const float* wsf = (const float*)ws;
  const __bf16* Dbf = (const __bf16*)((const char*)ws + 256);
  const __bf16* DTbf = (const __bf16*)((const char*)ws + 256 + 32768);

  __shared__ __align__(16) char arena[20480];
  char* smem = arena;

  const int tid = threadIdx.x;
  const int w = tid >> 6;
  const int lane = tid & 63;
  const int c = lane & 15;
  const int q4 = lane >> 4;
  const int q4h = q4 >> 1, q4l = q4 & 1;
  const int j0 = blockIdx.x * NCOL;

  // stage X tile straight into V-layout bf16 (coalesced float4 global reads)
#pragma unroll
  for (int e = 0; e < 8; ++e) {
    int idx = e * 256 + tid;                  // 2048 float4 = 256x32 tile
    int row = idx >> 3, c4 = (idx & 7) * 4;
    float4 g = *(const float4*)(X + row * NTOT + j0 + c4);
    int base = 4096 + (row >> 5) * 1024 + 256 * ((row >> 3) & 3) + (row & 7) * 2;
    float vals[4] = {g.x, g.y, g.z, g.w};
#pragma unroll
    for (int i = 0; i < 4; ++i) {
      int col = c4 + i;
      *(__bf16*)(smem + base + (col >> 4) * 8192 + (col & 15) * 16) = (__bf16)vals[i];
    }
  }

  const float eta = wsf[0];
  const f32x2 etav = f2(eta);
  const f32x2 metav = f2(-eta);
  const f32x2 cqv = f2(1.f - 0.1f * eta);
  const f32x2 cmv = f2(1.f - 1.1f * eta);
  const float tm = 0.1f * eta;

  // D fragments (iteration-invariant, VGPR-resident, from global/L2)
  bf16x8 d1[4][2];   // GEMM1 A: D rows [64w..64w+64), K=64
#pragma unroll
  for (int rt = 0; rt < 4; ++rt)
#pragma unroll
    for (int kb = 0; kb < 2; ++kb)
      d1[rt][kb] = *(const bf16x8*)(Dbf + (64 * w + 16 * rt + c) * 64 + 32 * kb + 8 * q4);
  bf16x8 d2[8];      // GEMM2 A: D^T rows [16w..16w+16), K=256
#pragma unroll
  for (int kb = 0; kb < 8; ++kb)
    d2[kb] = *(const bf16x8*)(DTbf + (16 * w + c) * 256 + 32 * kb + 8 * q4);

  __syncthreads();   // X staged

  const int rb = lane * 16;   // linear B-frag read base (conflict-free)

  // b0_q = eta * D^T x  (X already in B-frag layout)
  f32x2 bqt2[2][2];
#pragma unroll
  for (int ct = 0; ct < 2; ++ct) {
    f32x4 acc = {0.f, 0.f, 0.f, 0.f};
#pragma unroll
    for (int kb = 0; kb < 8; ++kb) {
      bf16x8 bx = *(const bf16x8*)(smem + rb + 4096 + ct * 8192 + kb * 1024);
      acc = MFMA16(d2[kb], bx, acc);
    }
    f32x2 a0 = {acc[0], acc[1]}, a1 = {acc[2], acc[3]};
    bqt2[ct][0] = etav * a0;   // t_q = 0
    bqt2[ct][1] = etav * a1;
  }

  // b0_m - t_m = eta*x - tm  (x from bf16 V-layout; 8B reads, 2-way max)
  f32x2 bmt2[4][2][2];
#pragma unroll
  for (int rt = 0; rt < 4; ++rt) {
    int r = 64 * w + 16 * rt + 4 * q4;
    int ao = 4096 + (r >> 5) * 1024 + (c + 16 * ((r >> 3) & 3)) * 16 + (r & 7) * 2;
#pragma unroll
    for (int ct = 0; ct < 2; ++ct) {
      bf16x4 xb = *(const bf16x4*)(smem + ao + ct * 8192);
      f32x2 x0 = {(float)xb[0], (float)xb[1]};
      f32x2 x1 = {(float)xb[2], (float)xb[3]};
      bmt2[rt][ct][0] = pfma(etav, x0, f2(-tm));
      bmt2[rt][ct][1] = pfma(etav, x1, f2(-tm));
    }
  }

  // z1 = relu(b0 - t)
  f32x2 zq2[2][2], zm2[4][2][2];
#pragma unroll
  for (int ct = 0; ct < 2; ++ct)
#pragma unroll
    for (int p = 0; p < 2; ++p) zq2[ct][p] = pmax0(bqt2[ct][p]);
#pragma unroll
  for (int rt = 0; rt < 4; ++rt)
#pragma unroll
    for (int ct = 0; ct < 2; ++ct)
#pragma unroll
      for (int p = 0; p < 2; ++p) zm2[rt][ct][p] = pmax0(bmt2[rt][ct][p]);

  // write offsets (C-layout -> B-frag layout), reads stay rb-linear
  const int wzq = (w >> 1) * 1024 + ((2 * w) & 3) * 256 + q4h * 256 + c * 16 + 8 * q4l;
  const int wvb = 4096 + 2 * w * 1024 + q4h * 256 + c * 16 + 8 * q4l;

  // publish z1_q (zqb region untouched by X staging)
#pragma unroll
  for (int ct = 0; ct < 2; ++ct) {
    uint2 u; u.x = pk2v(zq2[ct][0]); u.y = pk2v(zq2[ct][1]);
    *(uint2*)(smem + wzq + ct * 2048) = u;
  }

  for (int it = 0; it < 15; ++it) {
    __syncthreads();   // zqb ready; vb free (X reads / prior GEMM2 reads done)
    // GEMM1: U = D z_q ; z_m update ; publish V = u + z_m(old)
#pragma unroll
    for (int ct = 0; ct < 2; ++ct) {
      bf16x8 bz0 = *(const bf16x8*)(smem + rb + ct * 2048);
      bf16x8 bz1 = *(const bf16x8*)(smem + rb + ct * 2048 + 1024);
#pragma unroll
      for (int rt = 0; rt < 4; ++rt) {
        f32x4 acc = {0.f, 0.f, 0.f, 0.f};
        acc = MFMA16(d1[rt][0], bz0, acc);
        acc = MFMA16(d1[rt][1], bz1, acc);
        f32x2 u0 = {acc[0], acc[1]}, u1 = {acc[2], acc[3]};
        f32x2 z0 = zm2[rt][ct][0], z1 = zm2[rt][ct][1];
        f32x2 v0 = u0 + z0, v1 = u1 + z1;
        f32x2 t0 = pfma(cmv, z0, bmt2[rt][ct][0]);
        f32x2 t1 = pfma(cmv, z1, bmt2[rt][ct][1]);
        zm2[rt][ct][0] = pmax0(pfma(metav, u0, t0));
        zm2[rt][ct][1] = pmax0(pfma(metav, u1, t1));
        uint2 uu; uu.x = pk2v(v0); uu.y = pk2v(v1);
        *(uint2*)(smem + wvb + ct * 8192 + rt * 512) = uu;
      }
    }
    __syncthreads();   // vb ready; zqb free
    // GEMM2: w = D^T V ; z_q update ; publish
#pragma unroll
    for (int ct = 0; ct < 2; ++ct) {
      f32x4 acc = {0.f, 0.f, 0.f, 0.f};
#pragma unroll
      for (int kb = 0; kb < 8; ++kb) {
        bf16x8 bv = *(const bf16x8*)(smem + rb + 4096 + ct * 8192 + kb * 1024);
        acc = MFMA16(d2[kb], bv, acc);
      }
      f32x2 w0 = {acc[0], acc[1]}, w1 = {acc[2], acc[3]};
      f32x2 t0 = pfma(cqv, zq2[ct][0], bqt2[ct][0]);
      f32x2 t1 = pfma(cqv, zq2[ct][1], bqt2[ct][1]);
      zq2[ct][0] = pmax0(pfma(metav, w0, t0));
      zq2[ct][1] = pmax0(pfma(metav, w1, t1));
      uint2 u; u.x = pk2v(zq2[ct][0]); u.y = pk2v(zq2[ct][1]);
      *(uint2*)(smem + wzq + ct * 2048) = u;
    }
  }

  // store Z: rows 0..63 = q-part, rows 64..319 = m-part
#pragma unroll
  for (int ct = 0; ct < 2; ++ct)
#pragma unroll
    for (int p = 0; p < 2; ++p)
#pragma unroll
      for (int e = 0; e < 2; ++e)
        Z[(16 * w + 4 * q4 + 2 * p + e) * NTOT + j0 + 16 * ct + c] = zq2[ct][p][e];
#pragma unroll
  for (int rt = 0; rt < 4; ++rt)
#pragma unroll
    for (int ct = 0; ct < 2; ++ct)
#pragma unroll
      for (int p = 0; p < 2; ++p)
#pragma unroll
        for (int e = 0; e < 2; ++e)
          Z[(64 + 64 * w + 16 * rt + 4 * q4 + 2 * p + e) * NTOT + j0 + 16 * ct + c] = zm2[rt][ct][p][e];
}

extern "C" void kernel_launch(void* const* d_in, const int* in_sizes, int n_in,
                              void* d_out, int out_size, void* d_ws, size_t ws_size,
                              hipStream_t stream) {
  const float* X = (const float*)d_in[0];
  const float* D = (const float*)d_in[1];
  float* Z = (float*)d_out;
  rnmf_prep<<<dim3(1), dim3(256), 0, stream>>>(D, d_ws);
  rnmf_main<<<dim3(NTOT / NCOL), dim3(256), 0, stream>>>(X, Z, d_ws);
}